// Round 1
// baseline (230.156 us; speedup 1.0000x reference)
//
#include <hip/hip_runtime.h>

// ROIPatchExtractor: B=32, C=3, H=W=448, 2x2 patches -> N=128 samples.
// Pipeline per sample n (b=n>>2, gi=(n>>1)&1, gj=n&1):
//   patch = x[b, :, gi*224:(gi+1)*224, gj*224:(gj+1)*224]      (224x224)
//   up    = bilinear_resize(patch, 448x448)   (align_corners=False, clamped)
//   out   = bilinear_resize(up[top:top+ch, left:left+cw], 448x448)
// Both resizes are separable -> composed per-axis: each output row/col is a
// weighted sum of <=3 consecutive patch rows/cols. We precompute per-(n,t)
// entries {w0,w1,w2, base} in LDS and apply a separable 3x3 stencil.

#define IMG 448
#define PATCH 224
#define ROWS 8

__device__ inline float4 make_entry(int t, int crop, int off) {
    // stage 2: output coord t -> up-image coords u0,u1 with weight wy
    float cf = (float)crop;
    float s = ((float)t + 0.5f) * cf / 448.0f - 0.5f;
    s = fminf(fmaxf(s, 0.0f), cf - 1.0f);
    int i0 = (int)s;                 // s >= 0, trunc == floor
    int i1 = min(i0 + 1, crop - 1);
    float wy = s - (float)i0;
    int u0 = off + i0;
    int u1 = off + i1;
    // stage 1: up coord u -> patch coords (crop=224, out=448): s1 = 0.5*u - 0.25
    float t0 = fminf(fmaxf(0.5f * (float)u0 - 0.25f, 0.0f), 223.0f);
    int a0 = (int)t0;
    int a1 = min(a0 + 1, 223);
    float f0 = t0 - (float)a0;
    float t1 = fminf(fmaxf(0.5f * (float)u1 - 0.25f, 0.0f), 223.0f);
    int b0 = (int)t1;
    int b1 = min(b0 + 1, 223);
    float f1 = t1 - (float)b0;
    // accumulate 4 taps into 3 slots relative to a0 (footprint <= a0+2)
    float g0 = (1.0f - wy) * (1.0f - f0);
    float g1 = (1.0f - wy) * f0;
    float g2 = wy * (1.0f - f1);
    float g3 = wy * f1;
    float w0 = g0, w1 = 0.0f, w2 = 0.0f;
    if (a1 == a0) w0 += g1; else w1 += g1;
    if (b0 == a0) w0 += g2; else w1 += g2;
    int ob1 = b1 - a0;
    if (ob1 == 0) w0 += g3; else if (ob1 == 1) w1 += g3; else w2 += g3;
    float4 e;
    e.x = w0; e.y = w1; e.z = w2;
    e.w = __int_as_float(a0);        // patch-local base index [0,223]
    return e;
}

__global__ __launch_bounds__(448)
void roi_patch_kernel(const float* __restrict__ x,
                      const int* __restrict__ tops,
                      const int* __restrict__ lefts,
                      const int* __restrict__ crop_hs,
                      const int* __restrict__ crop_ws,
                      float* __restrict__ out,
                      int out_size) {
    __shared__ float4 colE[IMG];
    __shared__ float4 rowE[ROWS];

    const int n   = blockIdx.y;
    const int y0  = blockIdx.x * ROWS;
    const int tid = threadIdx.x;
    const int b   = n >> 2;
    const int gi  = (n >> 1) & 1;
    const int gj  = n & 1;

    const int ch = crop_hs[n], cw = crop_ws[n];
    const int tp = tops[n],    lf = lefts[n];

    colE[tid] = make_entry(tid, cw, lf);
    if (tid < ROWS) rowE[tid] = make_entry(y0 + tid, ch, tp);

    // patch_indices tail (float values; harness reads flat buffer as f32)
    if (blockIdx.x == 0 && n == 0 && tid < 128) {
        out[(size_t)out_size - 128 + tid] = (float)(tid & 3);
    }
    __syncthreads();

    const float4 ce = colE[tid];
    const int ca = __float_as_int(ce.w);
    const int cb = gj * PATCH;
    const int c0 = cb + ca;
    const int c1 = cb + min(ca + 1, 223);
    const int c2 = cb + min(ca + 2, 223);

    const float* xb = x + (size_t)b * 3 * IMG * IMG;
    float* ob = out + (size_t)n * 3 * IMG * IMG;

    for (int r = 0; r < ROWS; ++r) {
        const float4 re = rowE[r];
        const int ra = __float_as_int(re.w);
        const int rb = gi * PATCH;
        const int r0 = (rb + ra) * IMG;
        const int r1 = (rb + min(ra + 1, 223)) * IMG;
        const int r2 = (rb + min(ra + 2, 223)) * IMG;
        const int y = y0 + r;
        #pragma unroll
        for (int c = 0; c < 3; ++c) {
            const float* xc = xb + (size_t)c * IMG * IMG;
            float a0 = ce.x * xc[r0 + c0] + ce.y * xc[r0 + c1] + ce.z * xc[r0 + c2];
            float a1 = ce.x * xc[r1 + c0] + ce.y * xc[r1 + c1] + ce.z * xc[r1 + c2];
            float a2 = ce.x * xc[r2 + c0] + ce.y * xc[r2 + c1] + ce.z * xc[r2 + c2];
            ob[((size_t)c * IMG + y) * IMG + tid] = re.x * a0 + re.y * a1 + re.z * a2;
        }
    }
}

extern "C" void kernel_launch(void* const* d_in, const int* in_sizes, int n_in,
                              void* d_out, int out_size, void* d_ws, size_t ws_size,
                              hipStream_t stream) {
    const float* x        = (const float*)d_in[0];
    const int*   tops     = (const int*)d_in[1];
    const int*   lefts    = (const int*)d_in[2];
    const int*   crop_hs  = (const int*)d_in[3];
    const int*   crop_ws  = (const int*)d_in[4];
    float*       out      = (float*)d_out;

    dim3 grid(IMG / ROWS, 128);   // 56 x 128 blocks
    dim3 block(IMG);              // 448 threads = 7 waves
    roi_patch_kernel<<<grid, block, 0, stream>>>(x, tops, lefts, crop_hs, crop_ws,
                                                 out, out_size);
}

// Round 2
// 113.594 us; speedup vs baseline: 2.0261x; 2.0261x over previous
//
#include <hip/hip_runtime.h>

// ROIPatchExtractor: B=32, C=3, H=W=448, 2x2 patches -> N=128 samples.
// Per sample n (b=n>>2, gi=(n>>1)&1, gj=n&1):
//   patch = x[b, :, gi*224:(gi+1)*224, gj*224:(gj+1)*224]   (224x224)
//   up    = bilinear_resize(patch, 448x448)
//   out   = bilinear_resize(up[top:top+ch, left:left+cw], 448x448)
// Composed per axis: each output row/col = weighted sum of <=3 consecutive
// patch rows/cols. Two-pass separable within a block: horizontal pass
// interpolates each needed patch row ONCE into LDS, vertical pass combines
// 3 LDS rows per output pixel.

#define IMG 448
#define PATCH 224
#define ROWS 16
#define MAXPR 12   // max patch rows needed per 16 output rows (<= 8+3)

__device__ inline float4 make_entry(int t, int crop, int off) {
    // stage 2: output coord t -> up-image coords u0,u1 with weight wy
    float cf = (float)crop;
    float s = ((float)t + 0.5f) * cf / 448.0f - 0.5f;
    s = fminf(fmaxf(s, 0.0f), cf - 1.0f);
    int i0 = (int)s;                 // s >= 0, trunc == floor
    int i1 = min(i0 + 1, crop - 1);
    float wy = s - (float)i0;
    int u0 = off + i0;
    int u1 = off + i1;
    // stage 1: up coord u -> patch coord: s1 = 0.5*u - 0.25, clamp [0,223]
    float t0 = fminf(fmaxf(0.5f * (float)u0 - 0.25f, 0.0f), 223.0f);
    int a0 = (int)t0;
    int a1 = min(a0 + 1, 223);
    float f0 = t0 - (float)a0;
    float t1 = fminf(fmaxf(0.5f * (float)u1 - 0.25f, 0.0f), 223.0f);
    int b0 = (int)t1;
    int b1 = min(b0 + 1, 223);
    float f1 = t1 - (float)b0;
    // fold 4 taps into 3 slots relative to a0 (footprint <= a0+2)
    float g0 = (1.0f - wy) * (1.0f - f0);
    float g1 = (1.0f - wy) * f0;
    float g2 = wy * (1.0f - f1);
    float g3 = wy * f1;
    float w0 = g0, w1 = 0.0f, w2 = 0.0f;
    if (a1 == a0) w0 += g1; else w1 += g1;
    if (b0 == a0) w0 += g2; else w1 += g2;
    int ob1 = b1 - a0;
    if (ob1 == 0) w0 += g3; else if (ob1 == 1) w1 += g3; else w2 += g3;
    float4 e;
    e.x = w0; e.y = w1; e.z = w2;
    e.w = __int_as_float(a0);        // patch-local base index [0,223]
    return e;
}

__global__ __launch_bounds__(448)
void roi_patch_kernel(const float* __restrict__ x,
                      const int* __restrict__ tops,
                      const int* __restrict__ lefts,
                      const int* __restrict__ crop_hs,
                      const int* __restrict__ crop_ws,
                      float* __restrict__ out,
                      int out_size) {
    __shared__ float4 colE[IMG];
    __shared__ float4 rowE[ROWS];
    __shared__ float  hrow[MAXPR][IMG + 1];

    const int n   = blockIdx.y;
    const int y0  = blockIdx.x * ROWS;
    const int tid = threadIdx.x;
    const int b   = n >> 2;
    const int gi  = (n >> 1) & 1;
    const int gj  = n & 1;

    const int ch = crop_hs[n], cw = crop_ws[n];
    const int tp = tops[n],    lf = lefts[n];

    colE[tid] = make_entry(tid, cw, lf);
    if (tid < ROWS) rowE[tid] = make_entry(y0 + tid, ch, tp);

    // patch_indices tail (float values; harness reads flat buffer as f32)
    if (blockIdx.x == 0 && n == 0 && tid < 128) {
        out[(size_t)out_size - 128 + tid] = (float)(tid & 3);
    }
    __syncthreads();

    const float4 ce = colE[tid];
    const int ca = __float_as_int(ce.w);
    const int cb = gj * PATCH;
    const int c0 = cb + ca;
    const int c1 = cb + min(ca + 1, 223);
    const int c2 = cb + min(ca + 2, 223);

    // patch-row range needed by this block's 16 output rows (a0 monotone in y)
    const int pr_min = __float_as_int(rowE[0].w);
    const int pr_max = min(__float_as_int(rowE[ROWS - 1].w) + 2, 223);
    const int nrows  = pr_max - pr_min + 1;   // <= MAXPR

    const float* xb = x + (size_t)b * 3 * IMG * IMG;
    float* ob = out + (size_t)n * 3 * IMG * IMG;

    for (int c = 0; c < 3; ++c) {
        const float* xc = xb + ((size_t)c * IMG + gi * PATCH) * IMG;
        // horizontal pass: interpolate each needed patch row once
        for (int k = 0; k < nrows; ++k) {
            const float* xr = xc + (size_t)(pr_min + k) * IMG;
            hrow[k][tid] = ce.x * xr[c0] + ce.y * xr[c1] + ce.z * xr[c2];
        }
        __syncthreads();
        // vertical pass: 3 LDS taps per output pixel
        for (int r = 0; r < ROWS; ++r) {
            const float4 re = rowE[r];
            const int ra = __float_as_int(re.w);
            const int k0 = ra - pr_min;
            const int k1 = min(ra + 1, 223) - pr_min;
            const int k2 = min(ra + 2, 223) - pr_min;
            float v = re.x * hrow[k0][tid] + re.y * hrow[k1][tid]
                    + re.z * hrow[k2][tid];
            ob[((size_t)c * IMG + (y0 + r)) * IMG + tid] = v;
        }
        __syncthreads();
    }
}

extern "C" void kernel_launch(void* const* d_in, const int* in_sizes, int n_in,
                              void* d_out, int out_size, void* d_ws, size_t ws_size,
                              hipStream_t stream) {
    const float* x        = (const float*)d_in[0];
    const int*   tops     = (const int*)d_in[1];
    const int*   lefts    = (const int*)d_in[2];
    const int*   crop_hs  = (const int*)d_in[3];
    const int*   crop_ws  = (const int*)d_in[4];
    float*       out      = (float*)d_out;

    dim3 grid(IMG / ROWS, 128);   // 28 x 128 blocks
    dim3 block(IMG);              // 448 threads = 7 waves
    roi_patch_kernel<<<grid, block, 0, stream>>>(x, tops, lefts, crop_hs, crop_ws,
                                                 out, out_size);
}